// Round 3
// baseline (388.960 us; speedup 1.0000x reference)
//
#include <hip/hip_runtime.h>

typedef __bf16 bf16;
typedef __bf16 bf16x8 __attribute__((ext_vector_type(8)));
typedef float f32x4 __attribute__((ext_vector_type(4)));

#define DEV __device__ __forceinline__

// async global->LDS, 16B per lane. LDS dest must be wave-uniform base + lane*16.
DEV void gload16(const void* g, void* l) {
  __builtin_amdgcn_global_load_lds(
      (__attribute__((address_space(1))) void*)g,
      (__attribute__((address_space(3))) void*)l,
      16, 0, 0);
}

DEV unsigned pack_bf16(float a, float b) {
  union { bf16 h[2]; unsigned u; } u;
  u.h[0] = (bf16)a; u.h[1] = (bf16)b;
  return u.u;
}

// ---------------------------------------------------------------- fp32 -> bf16
__global__ __launch_bounds__(256) void cvt_f32_to_bf16(
    const float* __restrict__ in, bf16* __restrict__ out, long n) {
  long i = ((long)blockIdx.x * 256 + threadIdx.x) * 8;
  if (i + 8 > n) return;
  const float4* p = (const float4*)(in + i);
  float4 a = p[0], b = p[1];
  bf16x8 o;
  o[0] = (bf16)a.x; o[1] = (bf16)a.y; o[2] = (bf16)a.z; o[3] = (bf16)a.w;
  o[4] = (bf16)b.x; o[5] = (bf16)b.y; o[6] = (bf16)b.z; o[7] = (bf16)b.w;
  *(bf16x8*)(out + i) = o;
}

// ---------------------------------------------------------------- 8-phase 256x256 GEMM, C = A * B^T
// A: [M][K] bf16, B: [N][K] bf16, C: [M][N] OutT. BK=64, 8 waves (2Mx4N),
// per-wave 128x64 output = 8x4 frags. LDS 128KB double-buffered, XOR-chunk
// swizzle (both sides). Raw s_barrier + counted vmcnt (never 0 in steady loop).
// Requires M%256==0, N%256==0, K%64==0, K/64>=3.
template <typename OutT>
__global__ __launch_bounds__(512, 2) void gemm8p(
    const bf16* __restrict__ A, const bf16* __restrict__ B, OutT* __restrict__ C,
    int M, int N, int K) {
  __shared__ bf16 As[2][256 * 64];
  __shared__ bf16 Bs[2][256 * 64];
  const int tid = threadIdx.x;            // 0..511
  const int lane = tid & 63;
  const int wv = tid >> 6;                // 0..7
  const int wm = wv >> 2, wn = wv & 3;    // 2 x 4
  const int l15 = lane & 15, l4 = lane >> 4;
  const int swz7 = l15 & 7;
  const long m0 = (long)blockIdx.y * 256;
  const long n0 = (long)blockIdx.x * 256;
  const int NT = K >> 6;

  f32x4 acc[8][4];
#pragma unroll
  for (int i = 0; i < 8; ++i)
#pragma unroll
    for (int j = 0; j < 4; ++j) acc[i][j] = (f32x4){0.f, 0.f, 0.f, 0.f};

  // Stage one A-half (qm-stripes: rows q*64 within each 128-row block), 2 loads/thread.
  auto stageA = [&](int t, int q) {
#pragma unroll
    for (int it = 0; it < 2; ++it) {
      const int c = it * 512 + tid;                    // 0..1023
      const int row = ((c >> 9) << 7) + q * 64 + ((c >> 3) & 63);
      const int cc = c & 7;
      gload16(A + (m0 + row) * (long)K + t * 64 + ((cc ^ (row & 7)) << 3),
              &As[t & 1][row * 64 + cc * 8]);
    }
  };
  // Stage one B-half (qn-stripes: rows q*32 within each 64-row block), 2 loads/thread.
  auto stageB = [&](int t, int q) {
#pragma unroll
    for (int it = 0; it < 2; ++it) {
      const int c = it * 512 + tid;
      const int row = ((c >> 8) << 6) + q * 32 + ((c >> 3) & 31);
      const int cc = c & 7;
      gload16(B + (n0 + row) * (long)K + t * 64 + ((cc ^ (row & 7)) << 3),
              &Bs[t & 1][row * 64 + cc * 8]);
    }
  };

// One phase: ds-read quadrant (QM,QN) frags from buf CUR, issue STAGE, optional
// VM wait, barrier, lgkmcnt(0), 16 MFMA under setprio(1), barrier.
#define PHASE(CUR, QM, QN, STAGE, VM) do {                                      \
    __builtin_amdgcn_sched_barrier(0);                                          \
    bf16x8 af_[2][4], bf_[2][2];                                                \
    _Pragma("unroll")                                                           \
    for (int kk = 0; kk < 2; ++kk) {                                            \
      _Pragma("unroll")                                                         \
      for (int i = 0; i < 4; ++i)                                               \
        af_[kk][i] = *(const bf16x8*)&As[CUR][                                  \
            (wm * 128 + (QM) * 64 + i * 16 + l15) * 64 +                        \
            (((kk * 4 + l4) ^ swz7) << 3)];                                     \
      _Pragma("unroll")                                                         \
      for (int j = 0; j < 2; ++j)                                               \
        bf_[kk][j] = *(const bf16x8*)&Bs[CUR][                                  \
            (wn * 64 + (QN) * 32 + j * 16 + l15) * 64 +                         \
            (((kk * 4 + l4) ^ swz7) << 3)];                                     \
    }                                                                           \
    STAGE;                                                                      \
    VM;                                                                         \
    __builtin_amdgcn_sched_barrier(0);                                          \
    __builtin_amdgcn_s_barrier();                                               \
    asm volatile("s_waitcnt lgkmcnt(0)" ::: "memory");                          \
    __builtin_amdgcn_sched_barrier(0);                                          \
    __builtin_amdgcn_s_setprio(1);                                              \
    _Pragma("unroll")                                                           \
    for (int kk = 0; kk < 2; ++kk)                                              \
      _Pragma("unroll")                                                         \
      for (int i = 0; i < 4; ++i)                                               \
        _Pragma("unroll")                                                       \
        for (int j = 0; j < 2; ++j)                                             \
          acc[(QM) * 4 + i][(QN) * 2 + j] =                                     \
              __builtin_amdgcn_mfma_f32_16x16x32_bf16(                          \
                  af_[kk][i], bf_[kk][j], acc[(QM) * 4 + i][(QN) * 2 + j],      \
                  0, 0, 0);                                                     \
    __builtin_amdgcn_s_setprio(0);                                              \
    __builtin_amdgcn_s_barrier();                                               \
  } while (0)

  // Prologue: tile0 fully + tile1 A0,B0; wait leaves tile1's 2 half-stages in flight.
  stageA(0, 0); stageA(0, 1); stageB(0, 0); stageB(0, 1);
  stageA(1, 0); stageB(1, 0);
  asm volatile("s_waitcnt vmcnt(4)" ::: "memory");
  __builtin_amdgcn_sched_barrier(0);
  __builtin_amdgcn_s_barrier();

  // Steady state: stages p0->(T+1).A1, p1->(T+1).B1, p2->(T+2).A0, p3->(T+2).B0;
  // vmcnt(4) at p3 guarantees tile T+1 staged, keeps (T+2).A0/B0 in flight.
  for (int T = 0; T < NT - 2; ++T) {
    const int cur = T & 1;
    PHASE(cur, 0, 0, stageA(T + 1, 1), );
    PHASE(cur, 0, 1, stageB(T + 1, 1), );
    PHASE(cur, 1, 0, stageA(T + 2, 0), );
    PHASE(cur, 1, 1, stageB(T + 2, 0),
          asm volatile("s_waitcnt vmcnt(4)" ::: "memory"));
  }
  {  // T = NT-2: finish staging last tile; drain fully before entering it.
    const int cur = (NT - 2) & 1;
    PHASE(cur, 0, 0, stageA(NT - 1, 1), );
    PHASE(cur, 0, 1, stageB(NT - 1, 1), );
    PHASE(cur, 1, 0, , );
    PHASE(cur, 1, 1, , asm volatile("s_waitcnt vmcnt(0)" ::: "memory"));
  }
  {  // T = NT-1: compute only.
    const int cur = (NT - 1) & 1;
    PHASE(cur, 0, 0, , );
    PHASE(cur, 0, 1, , );
    PHASE(cur, 1, 0, , );
    PHASE(cur, 1, 1, , );
  }
#undef PHASE

#pragma unroll
  for (int i = 0; i < 8; ++i)
#pragma unroll
    for (int j = 0; j < 4; ++j) {
      const long row = m0 + wm * 128 + i * 16 + l4 * 4;
      const long col = n0 + wn * 64 + j * 16 + l15;
#pragma unroll
      for (int r = 0; r < 4; ++r)
        C[(row + r) * (long)N + col] = (OutT)acc[i][j][r];
    }
}

// ---------------------------------------------------------------- RMSNorm + RoPE for Q,K
__global__ __launch_bounds__(256) void qk_norm_rope(
    const bf16* __restrict__ qkv, const float* __restrict__ qw,
    const float* __restrict__ kw, bf16* __restrict__ Qh, bf16* __restrict__ Kh) {
  const int wg = blockIdx.x * 4 + (threadIdx.x >> 6);   // 0 .. 4096*40-1
  const int lane = threadIdx.x & 63;
  const int row = wg / 40;
  const int head = wg - row * 40;                       // 0..31 q, 32..39 k
  const int b = row >> 11, t = row & 2047;
  const bool is_q = head < 32;
  const int col0 = is_q ? head * 64 : 2048 + (head - 32) * 64;

  float v = (float)qkv[(long)row * 3072 + col0 + lane];
  float ss = v * v;
  ss += __shfl_xor(ss, 1);
  ss += __shfl_xor(ss, 2);
  ss += __shfl_xor(ss, 4);
  ss += __shfl_xor(ss, 8);
  ss += __shfl_xor(ss, 16);
  ss += __shfl_xor(ss, 32);
  const float norm = rsqrtf(ss * (1.0f / 64.0f) + 1e-6f);
  const float* wn = is_q ? qw : kw;
  float xn = v * norm * wn[lane];

  const int fi = lane & 31;
  const float inv_freq = expf(-(float)fi * (9.210340371976184f / 32.0f)); // ln(1e4)
  const float fr = (float)t * inv_freq;
  float sn, cs;
  sincosf(fr, &sn, &cs);
  const float xo = __shfl_xor(xn, 32);
  const float xr = (lane < 32) ? -xo : xo;
  const float res = xn * cs + xr * sn;

  if (is_q)
    Qh[(((long)b * 32 + head) * 2048 + t) * 64 + lane] = (bf16)res;
  else
    Kh[(((long)b * 8 + (head - 32)) * 2048 + t) * 64 + lane] = (bf16)res;
}

// ---------------------------------------------------------------- V transpose
__global__ __launch_bounds__(256) void v_transpose(
    const bf16* __restrict__ qkv, bf16* __restrict__ Vt) {
  const int bh = blockIdx.x;          // b*8 + kh
  const int t0 = blockIdx.y * 64;
  const int b = bh >> 3, kh = bh & 7;
  __shared__ bf16 tile[64][72];       // +8 pad
  const int tid = threadIdx.x;
#pragma unroll
  for (int it = 0; it < 2; ++it) {
    const int tt = it * 32 + (tid >> 3);
    const int d0 = (tid & 7) * 8;
    bf16x8 val = *(const bf16x8*)&qkv[((long)b * 2048 + t0 + tt) * 3072 + 2560 + kh * 64 + d0];
#pragma unroll
    for (int j = 0; j < 8; ++j) tile[tt][d0 + j] = val[j];
  }
  __syncthreads();
#pragma unroll
  for (int it = 0; it < 2; ++it) {
    const int d = it * 32 + (tid >> 3);
    const int tb = (tid & 7) * 8;
    bf16x8 o;
#pragma unroll
    for (int j = 0; j < 8; ++j) o[j] = tile[tb + j][d];
    *(bf16x8*)&Vt[((long)bh * 64 + d) * 2048 + t0 + tb] = o;
  }
}

// ---------------------------------------------------------------- causal flash attention
// Swapped-operand: S^T = K·Q^T, in-register softmax, P^T via shfl, O^T = V^T·P^T.
__global__ __launch_bounds__(256, 4) void attn_fwd(
    const bf16* __restrict__ Q, const bf16* __restrict__ K,
    const bf16* __restrict__ Vt, bf16* __restrict__ O) {
  const int b = blockIdx.x >> 5, h = blockIdx.x & 31;
  const int qb = 31 - (int)blockIdx.y;       // longest first
  const int q0 = qb * 64;
  const int kvh = h >> 2;
  const bf16* Qp = Q + (((long)b * 32 + h) * 2048 + q0) * 64;
  const bf16* Kp = K + ((long)b * 8 + kvh) * (2048L * 64);
  const bf16* Vp = Vt + ((long)b * 8 + kvh) * (64L * 2048);

  __shared__ bf16 Ks[64 * 64];   // [k][d], chunk-swizzled
  __shared__ bf16 Vs[64 * 64];   // [d][k], chunk-swizzled

  const int tid = threadIdx.x, lane = tid & 63, w = tid >> 6;
  const int l15 = lane & 15, l4 = lane >> 4;
  const int qwr = q0 + w * 16;               // wave's base q row
  const int q_g = qwr + l15;                 // this lane's q column

  bf16x8 qf[2];
#pragma unroll
  for (int kk = 0; kk < 2; ++kk)
    qf[kk] = *(const bf16x8*)(Qp + (w * 16 + l15) * 64 + kk * 32 + l4 * 8);

  f32x4 accO[4];                             // O^T: d = dn*16 + l4*4 + r, q = l15
#pragma unroll
  for (int dn = 0; dn < 4; ++dn) accO[dn] = (f32x4){0.f, 0.f, 0.f, 0.f};
  float M = -1e30f, L = 0.f;

  const float scale = 0.125f;
  const int swz = (l15 & 7) << 3;            // read-side XOR (bf16 units)

  for (int kt = 0; kt <= qb; ++kt) {
    const int k0 = kt * 64;
#pragma unroll
    for (int it = 0; it < 2; ++it) {
      const int c = it * 256 + tid;          // chunk 0..511 (16B each)
      const int row = c >> 3, cc = c & 7;
      const int scol = ((cc ^ (row & 7)) << 3);
      gload16(Kp + (long)(k0 + row) * 64 + scol, &Ks[c * 8]);
      gload16(Vp + (long)row * 2048 + k0 + scol, &Vs[c * 8]);
    }
    __syncthreads();

    f32x4 sT[4];
#pragma unroll
    for (int n = 0; n < 4; ++n) sT[n] = (f32x4){0.f, 0.f, 0.f, 0.f};
#pragma unroll
    for (int kk = 0; kk < 2; ++kk) {
      bf16x8 kf[4];
#pragma unroll
      for (int n = 0; n < 4; ++n)
        kf[n] = *(const bf16x8*)&Ks[(n * 16 + l15) * 64 + (((kk * 4 + l4) << 3) ^ swz)];
#pragma unroll
      for (int n = 0; n < 4; ++n)
        sT[n] = __builtin_amdgcn_mfma_f32_16x16x32_bf16(kf[n], qf[kk], sT[n], 0, 0, 0);
    }

    const bool edge = (kt == qb);
#pragma unroll
    for (int n = 0; n < 4; ++n) {
      const int kbase = k0 + n * 16 + l4 * 4;
#pragma unroll
      for (int r = 0; r < 4; ++r) {
        float v = sT[n][r] * scale;
        if (edge && (kbase + r > q_g)) v = -1e30f;
        sT[n][r] = v;
      }
    }

    float pm = -1e30f;
#pragma unroll
    for (int n = 0; n < 4; ++n)
#pragma unroll
      for (int r = 0; r < 4; ++r) pm = fmaxf(pm, sT[n][r]);
    pm = fmaxf(pm, __shfl_xor(pm, 16));
    pm = fmaxf(pm, __shfl_xor(pm, 32));
    const float newM = fmaxf(M, pm);
    const float sc = __expf(M - newM);
    M = newM;
    float rs = 0.f;
#pragma unroll
    for (int n = 0; n < 4; ++n)
#pragma unroll
      for (int r = 0; r < 4; ++r) {
        const float pv = __expf(sT[n][r] - newM);
        sT[n][r] = pv;
        rs += pv;
      }
    rs += __shfl_xor(rs, 16);
    rs += __shfl_xor(rs, 32);
    L = L * sc + rs;
#pragma unroll
    for (int dn = 0; dn < 4; ++dn) accO[dn] *= sc;

    unsigned lo[4], hi[4];
#pragma unroll
    for (int n = 0; n < 4; ++n) {
      lo[n] = pack_bf16(sT[n][0], sT[n][1]);
      hi[n] = pack_bf16(sT[n][2], sT[n][3]);
    }

    const int srcA = l15 | ((l4 & 1) << 5);
    const int srcB = srcA + 16;
    const bool selHi = (l4 >> 1);
#pragma unroll
    for (int kk = 0; kk < 2; ++kk) {
      unsigned d0a = __shfl(lo[2 * kk], srcA), d0b = __shfl(lo[2 * kk + 1], srcA);
      unsigned d1a = __shfl(hi[2 * kk], srcA), d1b = __shfl(hi[2 * kk + 1], srcA);
      unsigned d2a = __shfl(lo[2 * kk], srcB), d2b = __shfl(lo[2 * kk + 1], srcB);
      unsigned d3a = __shfl(hi[2 * kk], srcB), d3b = __shfl(hi[2 * kk + 1], srcB);
      union { unsigned d[4]; bf16x8 v; } pu;
      pu.d[0] = selHi ? d0b : d0a;
      pu.d[1] = selHi ? d1b : d1a;
      pu.d[2] = selHi ? d2b : d2a;
      pu.d[3] = selHi ? d3b : d3a;
      bf16x8 vf[4];
#pragma unroll
      for (int dn = 0; dn < 4; ++dn)
        vf[dn] = *(const bf16x8*)&Vs[(dn * 16 + l15) * 64 + (((kk * 4 + l4) << 3) ^ swz)];
#pragma unroll
      for (int dn = 0; dn < 4; ++dn)
        accO[dn] = __builtin_amdgcn_mfma_f32_16x16x32_bf16(vf[dn], pu.v, accO[dn], 0, 0, 0);
    }
    __syncthreads();
  }

  const float inv = 1.0f / L;
  const long rowbase = ((long)b * 2048 + q_g) * 2048 + h * 64;
#pragma unroll
  for (int dn = 0; dn < 4; ++dn)
#pragma unroll
    for (int rp = 0; rp < 2; ++rp) {
      const unsigned pk = pack_bf16(accO[dn][2 * rp] * inv, accO[dn][2 * rp + 1] * inv);
      *(unsigned*)&O[rowbase + dn * 16 + l4 * 4 + 2 * rp] = pk;
    }
}

// ----------------------------------------------------------------
extern "C" void kernel_launch(void* const* d_in, const int* in_sizes, int n_in,
                              void* d_out, int out_size, void* d_ws, size_t ws_size,
                              hipStream_t stream) {
  const float* x   = (const float*)d_in[0];
  const float* wq  = (const float*)d_in[1];
  const float* wk  = (const float*)d_in[2];
  const float* wv  = (const float*)d_in[3];
  const float* wo  = (const float*)d_in[4];
  const float* qnw = (const float*)d_in[5];
  const float* knw = (const float*)d_in[6];
  float* out = (float*)d_out;

  char* ws = (char*)d_ws;
  size_t off = 0;
  auto carve = [&](size_t bytes) -> void* {
    void* p = ws + off;
    off += (bytes + 255) & ~(size_t)255;
    return p;
  };
  bf16* xb    = (bf16*)carve(8388608ull * 2);    // x bf16 [4096][2048]; reused as attn_out
  bf16* wqkvb = (bf16*)carve(6291456ull * 2);    // [3072][2048]
  bf16* wob   = (bf16*)carve(4194304ull * 2);    // [2048][2048]
  bf16* qkvb  = (bf16*)carve(12582912ull * 2);   // [4096][3072]
  bf16* Qh    = (bf16*)carve(8388608ull * 2);    // [2][32][2048][64]
  bf16* Kh    = (bf16*)carve(2097152ull * 2);    // [2][8][2048][64]
  bf16* Vt    = (bf16*)carve(2097152ull * 2);    // [2][8][64][2048]

  cvt_f32_to_bf16<<<4096, 256, 0, stream>>>(x, xb, 8388608L);
  cvt_f32_to_bf16<<<2048, 256, 0, stream>>>(wq, wqkvb, 4194304L);
  cvt_f32_to_bf16<<<512, 256, 0, stream>>>(wk, wqkvb + 4194304, 1048576L);
  cvt_f32_to_bf16<<<512, 256, 0, stream>>>(wv, wqkvb + 5242880, 1048576L);
  cvt_f32_to_bf16<<<2048, 256, 0, stream>>>(wo, wob, 4194304L);

  gemm8p<bf16><<<dim3(12, 16), 512, 0, stream>>>(xb, wqkvb, qkvb, 4096, 3072, 2048);
  qk_norm_rope<<<40960, 256, 0, stream>>>(qkvb, qnw, knw, Qh, Kh);
  v_transpose<<<dim3(16, 32), 256, 0, stream>>>(qkvb, Vt);

  bf16* attnb = xb;   // xb is dead after the QKV GEMM
  attn_fwd<<<dim3(64, 32), 256, 0, stream>>>(Qh, Kh, Vt, attnb);

  gemm8p<float><<<dim3(8, 16), 512, 0, stream>>>(attnb, wob, out, 4096, 2048, 2048);
}

// Round 4
// 367.797 us; speedup vs baseline: 1.0575x; 1.0575x over previous
//
#include <hip/hip_runtime.h>

typedef __bf16 bf16;
typedef __bf16 bf16x8 __attribute__((ext_vector_type(8)));
typedef float f32x4 __attribute__((ext_vector_type(4)));

#define DEV __device__ __forceinline__

// async global->LDS, 16B per lane. LDS dest must be wave-uniform base + lane*16.
DEV void gload16(const void* g, void* l) {
  __builtin_amdgcn_global_load_lds(
      (__attribute__((address_space(1))) void*)g,
      (__attribute__((address_space(3))) void*)l,
      16, 0, 0);
}

DEV unsigned pack_bf16(float a, float b) {
  union { bf16 h[2]; unsigned u; } u;
  u.h[0] = (bf16)a; u.h[1] = (bf16)b;
  return u.u;
}

// ---------------------------------------------------------------- fused fp32 -> bf16
// 5 source arrays, ONE contiguous bf16 destination (xb|wqkvb|wob carves).
__global__ __launch_bounds__(256) void cvt_fused(
    const float* __restrict__ s0, const float* __restrict__ s1,
    const float* __restrict__ s2, const float* __restrict__ s3,
    const float* __restrict__ s4, bf16* __restrict__ out) {
  const long i = ((long)blockIdx.x * 256 + threadIdx.x) * 8;  // < 18874368
  const float* src;
  long off;
  if (i < 8388608)       { src = s0; off = i; }
  else if (i < 12582912) { src = s1; off = i - 8388608; }
  else if (i < 13631488) { src = s2; off = i - 12582912; }
  else if (i < 14680064) { src = s3; off = i - 13631488; }
  else                   { src = s4; off = i - 14680064; }
  const float4* p = (const float4*)(src + off);
  float4 a = p[0], b = p[1];
  bf16x8 o;
  o[0] = (bf16)a.x; o[1] = (bf16)a.y; o[2] = (bf16)a.z; o[3] = (bf16)a.w;
  o[4] = (bf16)b.x; o[5] = (bf16)b.y; o[6] = (bf16)b.z; o[7] = (bf16)b.w;
  *(bf16x8*)(out + i) = o;
}

// ---------------------------------------------------------------- RoPE cos/sin table
// tab[t*32+fi] = (cos, sin) of t * theta^(-fi/32).  65536 entries.
__global__ __launch_bounds__(256) void rope_table(float2* __restrict__ tab) {
  const int idx = blockIdx.x * 256 + threadIdx.x;
  const int t = idx >> 5, fi = idx & 31;
  const float invf = expf(-(float)fi * (9.210340371976184f / 32.0f)); // ln(1e4)/32
  float sn, cs;
  sincosf((float)t * invf, &sn, &cs);
  tab[idx] = make_float2(cs, sn);
}

// ---------------------------------------------------------------- 8-phase 256x256 GEMM, C = A * B^T
// + bijective XCD swizzle (requires gridDim.x*gridDim.y % 8 == 0).
template <typename OutT>
__global__ __launch_bounds__(512, 2) void gemm8p(
    const bf16* __restrict__ A, const bf16* __restrict__ B, OutT* __restrict__ C,
    int M, int N, int K) {
  __shared__ bf16 As[2][256 * 64];
  __shared__ bf16 Bs[2][256 * 64];
  const int tid = threadIdx.x;            // 0..511
  const int lane = tid & 63;
  const int wv = tid >> 6;                // 0..7
  const int wm = wv >> 2, wn = wv & 3;    // 2 x 4
  const int l15 = lane & 15, l4 = lane >> 4;
  const int swz7 = l15 & 7;

  // XCD-aware bijective block swizzle (T1)
  const int nx = gridDim.x;
  const int nwg = nx * gridDim.y;
  int wg = blockIdx.y * nx + blockIdx.x;
  wg = (wg & 7) * (nwg >> 3) + (wg >> 3);
  const long m0 = (long)(wg / nx) * 256;
  const long n0 = (long)(wg % nx) * 256;
  const int NT = K >> 6;

  f32x4 acc[8][4];
#pragma unroll
  for (int i = 0; i < 8; ++i)
#pragma unroll
    for (int j = 0; j < 4; ++j) acc[i][j] = (f32x4){0.f, 0.f, 0.f, 0.f};

  auto stageA = [&](int t, int q) {
#pragma unroll
    for (int it = 0; it < 2; ++it) {
      const int c = it * 512 + tid;                    // 0..1023
      const int row = ((c >> 9) << 7) + q * 64 + ((c >> 3) & 63);
      const int cc = c & 7;
      gload16(A + (m0 + row) * (long)K + t * 64 + ((cc ^ (row & 7)) << 3),
              &As[t & 1][row * 64 + cc * 8]);
    }
  };
  auto stageB = [&](int t, int q) {
#pragma unroll
    for (int it = 0; it < 2; ++it) {
      const int c = it * 512 + tid;
      const int row = ((c >> 8) << 6) + q * 32 + ((c >> 3) & 31);
      const int cc = c & 7;
      gload16(B + (n0 + row) * (long)K + t * 64 + ((cc ^ (row & 7)) << 3),
              &Bs[t & 1][row * 64 + cc * 8]);
    }
  };

#define PHASE(CUR, QM, QN, STAGE, VM) do {                                      \
    __builtin_amdgcn_sched_barrier(0);                                          \
    bf16x8 af_[2][4], bf_[2][2];                                                \
    _Pragma("unroll")                                                           \
    for (int kk = 0; kk < 2; ++kk) {                                            \
      _Pragma("unroll")                                                         \
      for (int i = 0; i < 4; ++i)                                               \
        af_[kk][i] = *(const bf16x8*)&As[CUR][                                  \
            (wm * 128 + (QM) * 64 + i * 16 + l15) * 64 +                        \
            (((kk * 4 + l4) ^ swz7) << 3)];                                     \
      _Pragma("unroll")                                                         \
      for (int j = 0; j < 2; ++j)                                               \
        bf_[kk][j] = *(const bf16x8*)&Bs[CUR][                                  \
            (wn * 64 + (QN) * 32 + j * 16 + l15) * 64 +                         \
            (((kk * 4 + l4) ^ swz7) << 3)];                                     \
    }                                                                           \
    STAGE;                                                                      \
    VM;                                                                         \
    __builtin_amdgcn_sched_barrier(0);                                          \
    __builtin_amdgcn_s_barrier();                                               \
    asm volatile("s_waitcnt lgkmcnt(0)" ::: "memory");                          \
    __builtin_amdgcn_sched_barrier(0);                                          \
    __builtin_amdgcn_s_setprio(1);                                              \
    _Pragma("unroll")                                                           \
    for (int kk = 0; kk < 2; ++kk)                                              \
      _Pragma("unroll")                                                         \
      for (int i = 0; i < 4; ++i)                                               \
        _Pragma("unroll")                                                       \
        for (int j = 0; j < 2; ++j)                                             \
          acc[(QM) * 4 + i][(QN) * 2 + j] =                                     \
              __builtin_amdgcn_mfma_f32_16x16x32_bf16(                          \
                  af_[kk][i], bf_[kk][j], acc[(QM) * 4 + i][(QN) * 2 + j],      \
                  0, 0, 0);                                                     \
    __builtin_amdgcn_s_setprio(0);                                              \
    __builtin_amdgcn_s_barrier();                                               \
  } while (0)

  stageA(0, 0); stageA(0, 1); stageB(0, 0); stageB(0, 1);
  stageA(1, 0); stageB(1, 0);
  asm volatile("s_waitcnt vmcnt(4)" ::: "memory");
  __builtin_amdgcn_sched_barrier(0);
  __builtin_amdgcn_s_barrier();

  for (int T = 0; T < NT - 2; ++T) {
    const int cur = T & 1;
    PHASE(cur, 0, 0, stageA(T + 1, 1), );
    PHASE(cur, 0, 1, stageB(T + 1, 1), );
    PHASE(cur, 1, 0, stageA(T + 2, 0), );
    PHASE(cur, 1, 1, stageB(T + 2, 0),
          asm volatile("s_waitcnt vmcnt(4)" ::: "memory"));
  }
  {
    const int cur = (NT - 2) & 1;
    PHASE(cur, 0, 0, stageA(NT - 1, 1), );
    PHASE(cur, 0, 1, stageB(NT - 1, 1), );
    PHASE(cur, 1, 0, , );
    PHASE(cur, 1, 1, , asm volatile("s_waitcnt vmcnt(0)" ::: "memory"));
  }
  {
    const int cur = (NT - 1) & 1;
    PHASE(cur, 0, 0, , );
    PHASE(cur, 0, 1, , );
    PHASE(cur, 1, 0, , );
    PHASE(cur, 1, 1, , );
  }
#undef PHASE

#pragma unroll
  for (int i = 0; i < 8; ++i)
#pragma unroll
    for (int j = 0; j < 4; ++j) {
      const long row = m0 + wm * 128 + i * 16 + l4 * 4;
      const long col = n0 + wn * 64 + j * 16 + l15;
#pragma unroll
      for (int r = 0; r < 4; ++r)
        C[(row + r) * (long)N + col] = (OutT)acc[i][j][r];
    }
}

// ---------------------------------------------------------------- RMSNorm + RoPE for Q,K
// Table-driven trig; Q output pre-scaled by 1/8 (RoPE is linear, softmax scale folded).
__global__ __launch_bounds__(256) void qk_norm_rope(
    const bf16* __restrict__ qkv, const float* __restrict__ qw,
    const float* __restrict__ kw, const float2* __restrict__ tab,
    bf16* __restrict__ Qh, bf16* __restrict__ Kh) {
  const int wg = blockIdx.x * 4 + (threadIdx.x >> 6);   // 0 .. 4096*40-1
  const int lane = threadIdx.x & 63;
  const int row = wg / 40;
  const int head = wg - row * 40;                       // 0..31 q, 32..39 k
  const int b = row >> 11, t = row & 2047;
  const bool is_q = head < 32;
  const int col0 = is_q ? head * 64 : 2048 + (head - 32) * 64;

  float v = (float)qkv[(long)row * 3072 + col0 + lane];
  float ss = v * v;
  ss += __shfl_xor(ss, 1);
  ss += __shfl_xor(ss, 2);
  ss += __shfl_xor(ss, 4);
  ss += __shfl_xor(ss, 8);
  ss += __shfl_xor(ss, 16);
  ss += __shfl_xor(ss, 32);
  const float norm = rsqrtf(ss * (1.0f / 64.0f) + 1e-6f);
  const float* wn = is_q ? qw : kw;
  float xn = v * norm * wn[lane];

  const int fi = lane & 31;
  const float2 cn = tab[t * 32 + fi];
  const float xo = __shfl_xor(xn, 32);
  const float xr = (lane < 32) ? -xo : xo;
  float res = xn * cn.x + xr * cn.y;

  if (is_q) {
    res *= 0.125f;                                      // softmax scale folded into Q
    Qh[(((long)b * 32 + head) * 2048 + t) * 64 + lane] = (bf16)res;
  } else {
    Kh[(((long)b * 8 + (head - 32)) * 2048 + t) * 64 + lane] = (bf16)res;
  }
}

// ---------------------------------------------------------------- V transpose
__global__ __launch_bounds__(256) void v_transpose(
    const bf16* __restrict__ qkv, bf16* __restrict__ Vt) {
  const int bh = blockIdx.x;          // b*8 + kh
  const int t0 = blockIdx.y * 64;
  const int b = bh >> 3, kh = bh & 7;
  __shared__ bf16 tile[64][72];       // +8 pad
  const int tid = threadIdx.x;
#pragma unroll
  for (int it = 0; it < 2; ++it) {
    const int tt = it * 32 + (tid >> 3);
    const int d0 = (tid & 7) * 8;
    bf16x8 val = *(const bf16x8*)&qkv[((long)b * 2048 + t0 + tt) * 3072 + 2560 + kh * 64 + d0];
#pragma unroll
    for (int j = 0; j < 8; ++j) tile[tt][d0 + j] = val[j];
  }
  __syncthreads();
#pragma unroll
  for (int it = 0; it < 2; ++it) {
    const int d = it * 32 + (tid >> 3);
    const int tb = (tid & 7) * 8;
    bf16x8 o;
#pragma unroll
    for (int j = 0; j < 8; ++j) o[j] = tile[tb + j][d];
    *(bf16x8*)&Vt[((long)bh * 64 + d) * 2048 + t0 + tb] = o;
  }
}

// ---------------------------------------------------------------- causal flash attention
// Swapped-operand, KVBLK=128, defer-max, Q pre-scaled. In-register softmax,
// P^T via shfl, O^T = V^T·P^T. K/V LDS chunk-swizzled (both sides).
__global__ __launch_bounds__(256, 4) void attn_fwd(
    const bf16* __restrict__ Q, const bf16* __restrict__ K,
    const bf16* __restrict__ Vt, bf16* __restrict__ O) {
  const int b = blockIdx.x >> 5, h = blockIdx.x & 31;
  const int qb = 31 - (int)blockIdx.y;       // longest first
  const int q0 = qb * 64;
  const int kvh = h >> 2;
  const bf16* Qp = Q + (((long)b * 32 + h) * 2048 + q0) * 64;
  const bf16* Kp = K + ((long)b * 8 + kvh) * (2048L * 64);
  const bf16* Vp = Vt + ((long)b * 8 + kvh) * (64L * 2048);

  __shared__ bf16 Ks[128 * 64];  // [k][d], chunk-swizzled (8 chunks/row)
  __shared__ bf16 Vs[64 * 128];  // [d][k], chunk-swizzled (16 chunks/row)

  const int tid = threadIdx.x, lane = tid & 63, w = tid >> 6;
  const int l15 = lane & 15, l4 = lane >> 4;
  const int swz7 = l15 & 7;
  const int qwr = q0 + w * 16;               // wave's base q row
  const int q_g = qwr + l15;                 // this lane's q column

  bf16x8 qf[2];
#pragma unroll
  for (int kk = 0; kk < 2; ++kk)
    qf[kk] = *(const bf16x8*)(Qp + (w * 16 + l15) * 64 + kk * 32 + l4 * 8);

  f32x4 accO[4];                             // O^T: d = dn*16 + l4*4 + r, q = l15
#pragma unroll
  for (int dn = 0; dn < 4; ++dn) accO[dn] = (f32x4){0.f, 0.f, 0.f, 0.f};
  float M = -1e30f, L = 0.f;

  const int NKT = (qb + 2) >> 1;             // 128-k tiles (last may be half-masked)
  for (int kt = 0; kt < NKT; ++kt) {
    const int k0 = kt * 128;
    // stage K [128][64] and V^T [64][128]; 4 chunks each per thread
#pragma unroll
    for (int it = 0; it < 4; ++it) {
      const int c = it * 256 + tid;          // 0..1023
      const int kr = c >> 3, kc = c & 7;
      gload16(Kp + (long)(k0 + kr) * 64 + ((kc ^ (kr & 7)) << 3), &Ks[c * 8]);
      const int vr = c >> 4, vc = c & 15;
      gload16(Vp + (long)vr * 2048 + k0 + ((vc ^ (vr & 7)) << 3), &Vs[c * 8]);
    }
    __syncthreads();

    // ---- S^T = K·Q^T : sT[n][r] = S[k0 + n*16 + l4*4 + r][q_g] (pre-scaled)
    f32x4 sT[8];
#pragma unroll
    for (int n = 0; n < 8; ++n) sT[n] = (f32x4){0.f, 0.f, 0.f, 0.f};
#pragma unroll
    for (int kk = 0; kk < 2; ++kk) {
      bf16x8 kf[8];
#pragma unroll
      for (int n = 0; n < 8; ++n)
        kf[n] = *(const bf16x8*)&Ks[(n * 16 + l15) * 64 + (((kk * 4 + l4) ^ swz7) << 3)];
#pragma unroll
      for (int n = 0; n < 8; ++n)
        sT[n] = __builtin_amdgcn_mfma_f32_16x16x32_bf16(kf[n], qf[kk], sT[n], 0, 0, 0);
    }

    // ---- causal mask (tail tiles only)
    if (k0 + 127 > qwr) {
#pragma unroll
      for (int n = 0; n < 8; ++n) {
        const int kbase = k0 + n * 16 + l4 * 4;
#pragma unroll
        for (int r = 0; r < 4; ++r)
          if (kbase + r > q_g) sT[n][r] = -1e30f;
      }
    }

    // ---- online softmax over k (column q_g); defer-max (T13)
    float pm = -1e30f;
#pragma unroll
    for (int n = 0; n < 8; ++n)
#pragma unroll
      for (int r = 0; r < 4; ++r) pm = fmaxf(pm, sT[n][r]);
    pm = fmaxf(pm, __shfl_xor(pm, 16));
    pm = fmaxf(pm, __shfl_xor(pm, 32));
    if (!__all(pm - M <= 8.0f)) {            // wave-uniform branch
      const float newM = fmaxf(M, pm);
      const float sc = __expf(M - newM);
      M = newM;
      L *= sc;
#pragma unroll
      for (int dn = 0; dn < 4; ++dn) accO[dn] *= sc;
    }
    float rs = 0.f;
#pragma unroll
    for (int n = 0; n < 8; ++n)
#pragma unroll
      for (int r = 0; r < 4; ++r) {
        const float pv = __expf(sT[n][r] - M);
        sT[n][r] = pv;
        rs += pv;
      }
    rs += __shfl_xor(rs, 16);
    rs += __shfl_xor(rs, 32);
    L += rs;

    // ---- pack P^T pairs: lo[n]=(r0,r1), hi[n]=(r2,r3) at k=k0+n*16+l4*4
    unsigned lo[8], hi[8];
#pragma unroll
    for (int n = 0; n < 8; ++n) {
      lo[n] = pack_bf16(sT[n][0], sT[n][1]);
      hi[n] = pack_bf16(sT[n][2], sT[n][3]);
    }

    // ---- PV: O^T += V^T · P^T  (B-frag of P^T assembled via shfl)
    const int srcA = l15 | ((l4 & 1) << 5);
    const int srcB = srcA + 16;
    const bool selHi = (l4 >> 1);
#pragma unroll
    for (int kk = 0; kk < 4; ++kk) {
      unsigned d0a = __shfl(lo[2 * kk], srcA), d0b = __shfl(lo[2 * kk + 1], srcA);
      unsigned d1a = __shfl(hi[2 * kk], srcA), d1b = __shfl(hi[2 * kk + 1], srcA);
      unsigned d2a = __shfl(lo[2 * kk], srcB), d2b = __shfl(lo[2 * kk + 1], srcB);
      unsigned d3a = __shfl(hi[2 * kk], srcB), d3b = __shfl(hi[2 * kk + 1], srcB);
      union { unsigned d[4]; bf16x8 v; } pu;
      pu.d[0] = selHi ? d0b : d0a;
      pu.d[1] = selHi ? d1b : d1a;
      pu.d[2] = selHi ? d2b : d2a;
      pu.d[3] = selHi ? d3b : d3a;
      bf16x8 vf[4];
#pragma unroll
      for (int dn = 0; dn < 4; ++dn)
        vf[dn] = *(const bf16x8*)&Vs[(dn * 16 + l15) * 128 + (((kk * 4 + l4) ^ swz7) << 3)];
#pragma unroll
      for (int dn = 0; dn < 4; ++dn)
        accO[dn] = __builtin_amdgcn_mfma_f32_16x16x32_bf16(vf[dn], pu.v, accO[dn], 0, 0, 0);
    }
    __syncthreads();
  }

  const float inv = 1.0f / L;
  const long rowbase = ((long)b * 2048 + q_g) * 2048 + h * 64;
#pragma unroll
  for (int dn = 0; dn < 4; ++dn)
#pragma unroll
    for (int rp = 0; rp < 2; ++rp) {
      const unsigned pk = pack_bf16(accO[dn][2 * rp] * inv, accO[dn][2 * rp + 1] * inv);
      *(unsigned*)&O[rowbase + dn * 16 + l4 * 4 + 2 * rp] = pk;
    }
}

// ----------------------------------------------------------------
extern "C" void kernel_launch(void* const* d_in, const int* in_sizes, int n_in,
                              void* d_out, int out_size, void* d_ws, size_t ws_size,
                              hipStream_t stream) {
  const float* x   = (const float*)d_in[0];
  const float* wq  = (const float*)d_in[1];
  const float* wk  = (const float*)d_in[2];
  const float* wv  = (const float*)d_in[3];
  const float* wo  = (const float*)d_in[4];
  const float* qnw = (const float*)d_in[5];
  const float* knw = (const float*)d_in[6];
  float* out = (float*)d_out;

  char* ws = (char*)d_ws;
  size_t off = 0;
  auto carve = [&](size_t bytes) -> void* {
    void* p = ws + off;
    off += (bytes + 255) & ~(size_t)255;
    return p;
  };
  // NOTE: xb|wqkvb|wob must stay contiguous (cvt_fused writes them as one run).
  bf16* xb    = (bf16*)carve(8388608ull * 2);    // x bf16 [4096][2048]; reused as attn_out
  bf16* wqkvb = (bf16*)carve(6291456ull * 2);    // [3072][2048]
  bf16* wob   = (bf16*)carve(4194304ull * 2);    // [2048][2048]
  bf16* qkvb  = (bf16*)carve(12582912ull * 2);   // [4096][3072]
  bf16* Qh    = (bf16*)carve(8388608ull * 2);    // [2][32][2048][64]
  bf16* Kh    = (bf16*)carve(2097152ull * 2);    // [2][8][2048][64]
  bf16* Vt    = (bf16*)carve(2097152ull * 2);    // [2][8][64][2048]
  float2* tab = (float2*)carve(65536ull * 8);    // rope cos/sin [2048][32]

  rope_table<<<256, 256, 0, stream>>>(tab);
  cvt_fused<<<9216, 256, 0, stream>>>(x, wq, wk, wv, wo, xb);

  gemm8p<bf16><<<dim3(12, 16), 512, 0, stream>>>(xb, wqkvb, qkvb, 4096, 3072, 2048);
  qk_norm_rope<<<40960, 256, 0, stream>>>(qkvb, qnw, knw, tab, Qh, Kh);
  v_transpose<<<dim3(16, 32), 256, 0, stream>>>(qkvb, Vt);

  bf16* attnb = xb;   // xb is dead after the QKV GEMM
  attn_fwd<<<dim3(64, 32), 256, 0, stream>>>(Qh, Kh, Vt, attnb);

  gemm8p<float><<<dim3(8, 16), 512, 0, stream>>>(attnb, wob, out, 4096, 2048, 2048);
}